// Round 6
// baseline (2133.816 us; speedup 1.0000x reference)
//
#include <hip/hip_runtime.h>

// No implicit FMA contraction anywhere; fused ops are written explicitly.
#pragma clang fp contract(off)

typedef unsigned char u8;

#define TSTEPS 4

// Fused (1x1 conv == channel matmul) + BatchNorm + LIF over time. FP32,
// replicating numpy-fp32 semantics bit-exactly under the model:
//   - einsum: per output element, ascending-c accumulation, FMA per step
//   - BN constants: correctly-rounded fp32 add/sqrt/div (via double emu)
//   - elementwise BN/LIF: separate fp32 roundings, reference op order
// XMODE: 0 = X1 is fp32, 1 = X1 is u8 spikes {0,1}
// HASX2: add u8 spike tensor X2 (fc1's x + attn_out; one fp32 rounded add,
//        = the reference's x = x + attn_out fp32 tensor)
// OMODE: 0 = write u8 spikes; 1 = fused final: out_f32 = (x + ao) + spike
template <int XMODE, bool HASX2, int OMODE>
__global__ __launch_bounds__(256) void conv_bn_lif(
    const void* __restrict__ X1v, const u8* __restrict__ X2,
    const float* __restrict__ Wt, const float* __restrict__ bias,
    const float* __restrict__ bnp,
    u8* __restrict__ Sout,                                    // OMODE 0
    const float* __restrict__ Xres, const u8* __restrict__ AOres,
    float* __restrict__ Fout,                                 // OMODE 1
    int Bsz, int Cin, int Cout, int N)
{
  const int tid = threadIdx.x;
  const int tx = tid & 15;
  const int ty = tid >> 4;
  const int nBase = blockIdx.x * 64;
  const int oBase = blockIdx.y * 64;
  const int b = blockIdx.z;

  __shared__ float Ws[16][68];
  __shared__ float Xs[16][68];

  // BN constants, each step correctly rounded to fp32 (double emulation is
  // exact for fp32 add/sqrt/div since 53 >= 2*24+2):
  //   d = fl32(v + fl32(1e-5)); s = fl32(sqrt(d)); ratio = fl32(g/s)
  float sc[4], mn[4], bt[4], bi[4];
  #pragma unroll
  for (int i = 0; i < 4; ++i) {
    int o = oBase + ty * 4 + i;
    float g  = bnp[0 * Cout + o];
    float be = bnp[1 * Cout + o];
    float m  = bnp[2 * Cout + o];
    float vv = bnp[3 * Cout + o];
    float d_f = (float)((double)vv + (double)1e-5f);
    float s_f = (float)sqrt((double)d_f);
    sc[i] = (float)((double)g / (double)s_f);
    mn[i] = m;
    bt[i] = be;
    bi[i] = bias ? bias[o] : 0.0f;
  }

  float mem[4][4];
  #pragma unroll
  for (int i = 0; i < 4; ++i)
    #pragma unroll
    for (int j = 0; j < 4; ++j) mem[i][j] = 0.0f;

  const int ldN = tid & 63;       // X loader: col (coalesced)
  const int ldK = tid >> 6;       // X loader: row group (0..3)
  const int wK  = tid & 15;       // W loader: k
  const int wO  = (tid >> 4) * 4; // W loader: o group

  for (int t = 0; t < TSTEPS; ++t) {
    float acc[4][4];
    #pragma unroll
    for (int i = 0; i < 4; ++i)
      #pragma unroll
      for (int j = 0; j < 4; ++j) acc[i][j] = 0.0f;

    const size_t xbase = (size_t)(t * Bsz + b) * Cin * N;

    for (int k0 = 0; k0 < Cin; k0 += 16) {
      __syncthreads();
      #pragma unroll
      for (int i = 0; i < 4; ++i) {
        int kk = ldK * 4 + i;
        size_t gx = xbase + (size_t)(k0 + kk) * N + nBase + ldN;
        float xv;
        if (XMODE == 0) xv = ((const float*)X1v)[gx];
        else            xv = (float)(((const u8*)X1v)[gx]);
        if (HASX2)      xv = xv + (float)X2[gx];  // one fp32 rounded add
        Xs[kk][ldN] = xv;
      }
      #pragma unroll
      for (int i = 0; i < 4; ++i) {
        int oo = wO + i;
        Ws[wK][oo] = Wt[(size_t)(oBase + oo) * Cin + k0 + wK];
      }
      __syncthreads();

      #pragma unroll
      for (int kk = 0; kk < 16; ++kk) {   // ascending c, FMA per step
        float wv[4], xv[4];
        #pragma unroll
        for (int i = 0; i < 4; ++i) wv[i] = Ws[kk][ty * 4 + i];
        #pragma unroll
        for (int j = 0; j < 4; ++j) xv[j] = Xs[kk][tx * 4 + j];
        #pragma unroll
        for (int i = 0; i < 4; ++i)
          #pragma unroll
          for (int j = 0; j < 4; ++j)
            acc[i][j] = fmaf(wv[i], xv[j], acc[i][j]);  // fused, 1 rounding
      }
    }

    // epilogue: bias + BN + LIF + store, strict fp32 reference op order,
    // separate roundings (no FMA: file-wide contract(off))
    const size_t sbase = (size_t)(t * Bsz + b) * Cout * N;
    #pragma unroll
    for (int i = 0; i < 4; ++i) {
      int o = oBase + ty * 4 + i;
      #pragma unroll
      for (int j = 0; j < 4; ++j) {
        float y = acc[i][j];
        if (bias) y = y + bi[i];
        float t1 = y - mn[i];
        float t2 = t1 * sc[i];
        y = t2 + bt[i];                            // BN
        float m2 = mem[i][j];
        float d = y - m2;
        m2 = m2 + d * 0.5f;                        // mem += (x-mem)/2, exact /2
        float s = (m2 - 0.5f) > 0.0f ? 1.0f : 0.0f;
        mem[i][j] = (s > 0.0f) ? 0.0f : m2;        // hard reset
        size_t idx = sbase + (size_t)o * N + nBase + tx * 4 + j;
        if (OMODE == 0) {
          Sout[idx] = (s > 0.0f) ? (u8)1 : (u8)0;
        } else {
          float xn = Xres[idx] + (float)AOres[idx];  // x + attn_out
          Fout[idx] = xn + s;                        // + m
        }
      }
    }
  }
}

// Attention (no softmax, spikes in) + attn-LIF, reassociated as q @ (k^T v):
// all values are exact dyadic rationals in fp32 => bitwise equal to the
// reference's (q k^T) v under any order. Pure integer arithmetic inside.
__global__ __launch_bounds__(256) void attn_lif(
    const u8* __restrict__ Qs, const u8* __restrict__ Ks,
    const u8* __restrict__ Vs, u8* __restrict__ Rs,
    int Bsz, int C, int N)
{
  const int tid = threadIdx.x;
  const int h = blockIdx.x & 15;
  const int b = blockIdx.x >> 4;

  __shared__ u8 qs[16][528];
  __shared__ u8 ks[16][528];
  __shared__ u8 vs[16][528];
  __shared__ int Gs[16][17];

  const int eG = tid >> 4;   // G row (e)
  const int dG = tid & 15;   // G col (d)
  const int dR = tid >> 4;   // owned d in r-phase
  const int nR0 = tid & 15;  // owned n residue

  float mem[32];
  #pragma unroll
  for (int i = 0; i < 32; ++i) mem[i] = 0.0f;

  for (int t = 0; t < TSTEPS; ++t) {
    __syncthreads();
    const size_t base = ((size_t)(t * Bsz + b) * C + h * 16) * N;
    for (int i = 0; i < 32; ++i) {
      int flat = tid + 256 * i;          // 0..8191 = 16*512
      int d = flat >> 9, n = flat & 511;
      size_t g = base + (size_t)d * N + n;
      qs[d][n] = Qs[g];
      ks[d][n] = Ks[g];
      vs[d][n] = Vs[g];
    }
    __syncthreads();

    int gi = 0;
    for (int n = 0; n < 512; ++n)
      gi += (int)ks[eG][n] * (int)vs[dG][n];
    Gs[eG][dG] = gi;
    __syncthreads();

    int Greg[16];
    #pragma unroll
    for (int e = 0; e < 16; ++e) Greg[e] = Gs[e][dR];

    const size_t obase = ((size_t)(t * Bsz + b) * C + h * 16 + dR) * N;
    for (int j = 0; j < 32; ++j) {
      int n = nR0 + 16 * j;
      int ri = 0;
      #pragma unroll
      for (int e = 0; e < 16; ++e)
        ri += qs[e][n] ? Greg[e] : 0;
      float r = (float)ri * 0.0625f;      // exact dyadic
      float m2 = mem[j];
      float d = r - m2;
      m2 = m2 + d * 0.5f;                 // exact (denominators <= 2^8)
      float s = (m2 - 0.5f) > 0.0f ? 1.0f : 0.0f;
      mem[j] = (s > 0.0f) ? 0.0f : m2;
      Rs[obase + n] = (s > 0.0f) ? (u8)1 : (u8)0;
    }
  }
}

extern "C" void kernel_launch(void* const* d_in, const int* in_sizes, int n_in,
                              void* d_out, int out_size, void* d_ws, size_t ws_size,
                              hipStream_t stream)
{
  const float* x     = (const float*)d_in[0];
  const float* q_w   = (const float*)d_in[1];
  const float* q_bn  = (const float*)d_in[2];
  const float* k_w   = (const float*)d_in[3];
  const float* k_bn  = (const float*)d_in[4];
  const float* v_w   = (const float*)d_in[5];
  const float* v_bn  = (const float*)d_in[6];
  const float* p_w   = (const float*)d_in[7];
  const float* p_bn  = (const float*)d_in[8];
  const float* f1_w  = (const float*)d_in[9];
  const float* f1_b  = (const float*)d_in[10];
  const float* f1_bn = (const float*)d_in[11];
  const float* f2_w  = (const float*)d_in[12];
  const float* f2_b  = (const float*)d_in[13];
  const float* f2_bn = (const float*)d_in[14];

  const int T = 4, B = 16, C = 256, N = 512, Hm = 1024;
  const size_t SZ = (size_t)T * B * C * N;  // 8388608 elems; u8 buffers

  // Workspace (u8 spikes), peak 5*SZ = 41.9 MB:
  //   [0,SZ) q  [SZ,2SZ) k  [2SZ,3SZ) v  [3SZ,4SZ) r  [4SZ,5SZ) ao
  //   h = (T,B,1024,N) u8 = 4*SZ overlays [0,4SZ): q/k/v/r dead by fc1
  char* ws = (char*)d_ws;
  u8* q_s  = (u8*)(ws + 0 * SZ);
  u8* k_s  = (u8*)(ws + 1 * SZ);
  u8* v_s  = (u8*)(ws + 2 * SZ);
  u8* r_s  = (u8*)(ws + 3 * SZ);
  u8* ao_s = (u8*)(ws + 4 * SZ);
  u8* h_s  = (u8*)(ws + 0 * SZ);

  dim3 blk(256);
  dim3 gC(N / 64, C / 64, B);

  conv_bn_lif<0, false, 0><<<gC, blk, 0, stream>>>(
      x, nullptr, q_w, nullptr, q_bn, q_s, nullptr, nullptr, nullptr, B, C, C, N);
  conv_bn_lif<0, false, 0><<<gC, blk, 0, stream>>>(
      x, nullptr, k_w, nullptr, k_bn, k_s, nullptr, nullptr, nullptr, B, C, C, N);
  conv_bn_lif<0, false, 0><<<gC, blk, 0, stream>>>(
      x, nullptr, v_w, nullptr, v_bn, v_s, nullptr, nullptr, nullptr, B, C, C, N);
  attn_lif<<<dim3(B * 16), blk, 0, stream>>>(q_s, k_s, v_s, r_s, B, C, N);
  conv_bn_lif<1, false, 0><<<gC, blk, 0, stream>>>(
      r_s, nullptr, p_w, nullptr, p_bn, ao_s, nullptr, nullptr, nullptr, B, C, C, N);
  conv_bn_lif<0, true, 0><<<dim3(N / 64, Hm / 64, B), blk, 0, stream>>>(
      x, ao_s, f1_w, f1_b, f1_bn, h_s, nullptr, nullptr, nullptr, B, C, Hm, N);
  conv_bn_lif<1, false, 1><<<gC, blk, 0, stream>>>(
      h_s, nullptr, f2_w, f2_b, f2_bn, nullptr, x, ao_s, (float*)d_out, B, Hm, C, N);
}

// Round 7
// 984.944 us; speedup vs baseline: 2.1664x; 2.1664x over previous
//
#include <hip/hip_runtime.h>

// numpy-fp32 semantics: explicit fmaf only, no implicit contraction.
#pragma clang fp contract(off)

typedef unsigned char u8;
typedef unsigned int u32;

#define TSTEPS 4

// Fused (1x1 conv) + BN + LIF, fp32, bit-exact ascending-k FMA chain.
// Software-pipelined: BK=32 double-buffered LDS, global->reg prefetch of
// tile i+1 during compute of tile i. Tile 64o x 64n, 256 thr, 4x4/thread.
// XMODE: 0 = X1 fp32, 1 = X1 u8 spikes. HASX2: add u8 X2 (fc1: x+attn_out).
// OMODE: 0 = u8 spike out; 1 = fused final out_f32 = (x + ao) + spike.
template <int XMODE, bool HASX2, int OMODE>
__global__ __launch_bounds__(256) void conv_bn_lif(
    const void* __restrict__ X1v, const u8* __restrict__ X2,
    const float* __restrict__ Wt, const float* __restrict__ bias,
    const float* __restrict__ bnp,
    u8* __restrict__ Sout,
    const float* __restrict__ Xres, const u8* __restrict__ AOres,
    float* __restrict__ Fout,
    int Bsz, int Cin, int Cout, int N)
{
  const int tid = threadIdx.x;
  const int tx = tid & 15, ty = tid >> 4;
  const int nBase = blockIdx.x * 64, oBase = blockIdx.y * 64, b = blockIdx.z;
  const int KT = Cin >> 5;          // k-tiles of 32
  const int TT = TSTEPS * KT;

  __shared__ __align__(16) float Xs[2][32][68];  // [buf][k][n]
  __shared__ __align__(16) float Ws[2][32][68];  // [buf][k][o]

  // BN constants, correctly-rounded fp32 (double emu exact for add/sqrt/div)
  float sc[4], mn[4], bt[4], bi[4];
  #pragma unroll
  for (int i = 0; i < 4; ++i) {
    int o = oBase + ty * 4 + i;
    float g  = bnp[0 * Cout + o];
    float be = bnp[1 * Cout + o];
    float m  = bnp[2 * Cout + o];
    float vv = bnp[3 * Cout + o];
    float d_f = (float)((double)vv + (double)1e-5f);
    float s_f = (float)sqrt((double)d_f);
    sc[i] = (float)((double)g / (double)s_f);
    mn[i] = m; bt[i] = be;
    bi[i] = bias ? bias[o] : 0.0f;
  }

  float mem[4][4], acc[4][4];
  #pragma unroll
  for (int i = 0; i < 4; ++i)
    #pragma unroll
    for (int j = 0; j < 4; ++j) { mem[i][j] = 0.0f; acc[i][j] = 0.0f; }

  // loader coords: X: 8 consecutive floats of one k-row; W: 8 consecutive k
  const int xRow = tid >> 3;        // 0..31
  const int xC8  = (tid & 7) * 8;   // 0..56
  const int wO   = tid >> 2;        // 0..63
  const int wK8  = (tid & 3) * 8;   // 0..24

  float4 pxa, pxb, pwa, pwb;        // prefetch registers
  uint2 pxu, pau;

  auto issue = [&](int i) {
    const int tI = i / KT, k0 = (i % KT) << 5;
    const size_t xb = (size_t)(tI * Bsz + b) * Cin * N
                    + (size_t)(k0 + xRow) * N + nBase + xC8;
    if constexpr (XMODE == 0) {
      pxa = *(const float4*)((const float*)X1v + xb);
      pxb = *(const float4*)((const float*)X1v + xb + 4);
    } else {
      pxu = *(const uint2*)((const u8*)X1v + xb);
    }
    if constexpr (HASX2) pau = *(const uint2*)(X2 + xb);
    const size_t wb = (size_t)(oBase + wO) * Cin + k0 + wK8;
    pwa = *(const float4*)(Wt + wb);
    pwb = *(const float4*)(Wt + wb + 4);
  };

  auto commit = [&](int buf) {
    float xv[8];
    if constexpr (XMODE == 0) {
      xv[0] = pxa.x; xv[1] = pxa.y; xv[2] = pxa.z; xv[3] = pxa.w;
      xv[4] = pxb.x; xv[5] = pxb.y; xv[6] = pxb.z; xv[7] = pxb.w;
    } else {
      #pragma unroll
      for (int j = 0; j < 4; ++j) xv[j]     = (float)((pxu.x >> (8 * j)) & 0xffu);
      #pragma unroll
      for (int j = 0; j < 4; ++j) xv[4 + j] = (float)((pxu.y >> (8 * j)) & 0xffu);
    }
    if constexpr (HASX2) {
      #pragma unroll
      for (int j = 0; j < 4; ++j) xv[j]     = xv[j]     + (float)((pau.x >> (8 * j)) & 0xffu);
      #pragma unroll
      for (int j = 0; j < 4; ++j) xv[4 + j] = xv[4 + j] + (float)((pau.y >> (8 * j)) & 0xffu);
    }
    *(float4*)&Xs[buf][xRow][xC8]     = make_float4(xv[0], xv[1], xv[2], xv[3]);
    *(float4*)&Xs[buf][xRow][xC8 + 4] = make_float4(xv[4], xv[5], xv[6], xv[7]);
    Ws[buf][wK8 + 0][wO] = pwa.x;  Ws[buf][wK8 + 1][wO] = pwa.y;
    Ws[buf][wK8 + 2][wO] = pwa.z;  Ws[buf][wK8 + 3][wO] = pwa.w;
    Ws[buf][wK8 + 4][wO] = pwb.x;  Ws[buf][wK8 + 5][wO] = pwb.y;
    Ws[buf][wK8 + 6][wO] = pwb.z;  Ws[buf][wK8 + 7][wO] = pwb.w;
  };

  issue(0);
  commit(0);
  __syncthreads();

  for (int tt = 0; tt < TT; ++tt) {
    const int buf = tt & 1;
    if (tt + 1 < TT) issue(tt + 1);   // overlap global latency with compute

    #pragma unroll
    for (int kk = 0; kk < 32; ++kk) { // ascending k, FMA chain (bit-exact)
      float4 wv = *(const float4*)&Ws[buf][kk][ty * 4];
      float4 xv = *(const float4*)&Xs[buf][kk][tx * 4];
      float wa[4] = {wv.x, wv.y, wv.z, wv.w};
      float xa[4] = {xv.x, xv.y, xv.z, xv.w};
      #pragma unroll
      for (int i = 0; i < 4; ++i)
        #pragma unroll
        for (int j = 0; j < 4; ++j)
          acc[i][j] = fmaf(wa[i], xa[j], acc[i][j]);
    }

    if ((tt % KT) == KT - 1) {
      // epilogue for timestep t (identical op order to the verified R6)
      const int t = tt / KT;
      const size_t sbase = (size_t)(t * Bsz + b) * Cout * N;
      #pragma unroll
      for (int i = 0; i < 4; ++i) {
        const size_t rb = sbase + (size_t)(oBase + ty * 4 + i) * N + nBase + tx * 4;
        if constexpr (OMODE == 0) {
          u32 pack = 0;
          #pragma unroll
          for (int j = 0; j < 4; ++j) {
            float y = acc[i][j];
            if (bias) y = y + bi[i];
            float t1 = y - mn[i];
            float t2 = t1 * sc[i];
            y = t2 + bt[i];
            float m2 = mem[i][j];
            float dd = y - m2;
            m2 = m2 + dd * 0.5f;
            bool sp = (m2 - 0.5f) > 0.0f;
            mem[i][j] = sp ? 0.0f : m2;
            if (sp) pack |= (1u << (8 * j));
            acc[i][j] = 0.0f;
          }
          *(u32*)&Sout[rb] = pack;
        } else {
          float4 xr = *(const float4*)&Xres[rb];
          u32 av = *(const u32*)&AOres[rb];
          float xa4[4] = {xr.x, xr.y, xr.z, xr.w};
          float o4[4];
          #pragma unroll
          for (int j = 0; j < 4; ++j) {
            float y = acc[i][j];
            if (bias) y = y + bi[i];
            float t1 = y - mn[i];
            float t2 = t1 * sc[i];
            y = t2 + bt[i];
            float m2 = mem[i][j];
            float dd = y - m2;
            m2 = m2 + dd * 0.5f;
            bool sp = (m2 - 0.5f) > 0.0f;
            mem[i][j] = sp ? 0.0f : m2;
            float s = sp ? 1.0f : 0.0f;
            float xn = xa4[j] + (float)((av >> (8 * j)) & 0xffu);
            o4[j] = xn + s;
            acc[i][j] = 0.0f;
          }
          *(float4*)&Fout[rb] = make_float4(o4[0], o4[1], o4[2], o4[3]);
        }
      }
    }

    __syncthreads();
    if (tt + 1 < TT) commit((tt + 1) & 1);
    __syncthreads();
  }
}

// Attention + attn-LIF, q @ (k^T v): integer-exact (unchanged, verified R6).
__global__ __launch_bounds__(256) void attn_lif(
    const u8* __restrict__ Qs, const u8* __restrict__ Ks,
    const u8* __restrict__ Vs, u8* __restrict__ Rs,
    int Bsz, int C, int N)
{
  const int tid = threadIdx.x;
  const int h = blockIdx.x & 15;
  const int b = blockIdx.x >> 4;

  __shared__ u8 qs[16][528];
  __shared__ u8 ks[16][528];
  __shared__ u8 vs[16][528];
  __shared__ int Gs[16][17];

  const int eG = tid >> 4;
  const int dG = tid & 15;
  const int dR = tid >> 4;
  const int nR0 = tid & 15;

  float mem[32];
  #pragma unroll
  for (int i = 0; i < 32; ++i) mem[i] = 0.0f;

  for (int t = 0; t < TSTEPS; ++t) {
    __syncthreads();
    const size_t base = ((size_t)(t * Bsz + b) * C + h * 16) * N;
    for (int i = 0; i < 32; ++i) {
      int flat = tid + 256 * i;
      int d = flat >> 9, n = flat & 511;
      size_t g = base + (size_t)d * N + n;
      qs[d][n] = Qs[g];
      ks[d][n] = Ks[g];
      vs[d][n] = Vs[g];
    }
    __syncthreads();

    int gi = 0;
    for (int n = 0; n < 512; ++n)
      gi += (int)ks[eG][n] * (int)vs[dG][n];
    Gs[eG][dG] = gi;
    __syncthreads();

    int Greg[16];
    #pragma unroll
    for (int e = 0; e < 16; ++e) Greg[e] = Gs[e][dR];

    const size_t obase = ((size_t)(t * Bsz + b) * C + h * 16 + dR) * N;
    for (int j = 0; j < 32; ++j) {
      int n = nR0 + 16 * j;
      int ri = 0;
      #pragma unroll
      for (int e = 0; e < 16; ++e)
        ri += qs[e][n] ? Greg[e] : 0;
      float r = (float)ri * 0.0625f;
      float m2 = mem[j];
      float d = r - m2;
      m2 = m2 + d * 0.5f;
      float s = (m2 - 0.5f) > 0.0f ? 1.0f : 0.0f;
      mem[j] = (s > 0.0f) ? 0.0f : m2;
      Rs[obase + n] = (s > 0.0f) ? (u8)1 : (u8)0;
    }
  }
}

extern "C" void kernel_launch(void* const* d_in, const int* in_sizes, int n_in,
                              void* d_out, int out_size, void* d_ws, size_t ws_size,
                              hipStream_t stream)
{
  const float* x     = (const float*)d_in[0];
  const float* q_w   = (const float*)d_in[1];
  const float* q_bn  = (const float*)d_in[2];
  const float* k_w   = (const float*)d_in[3];
  const float* k_bn  = (const float*)d_in[4];
  const float* v_w   = (const float*)d_in[5];
  const float* v_bn  = (const float*)d_in[6];
  const float* p_w   = (const float*)d_in[7];
  const float* p_bn  = (const float*)d_in[8];
  const float* f1_w  = (const float*)d_in[9];
  const float* f1_b  = (const float*)d_in[10];
  const float* f1_bn = (const float*)d_in[11];
  const float* f2_w  = (const float*)d_in[12];
  const float* f2_b  = (const float*)d_in[13];
  const float* f2_bn = (const float*)d_in[14];

  const int T = 4, B = 16, C = 256, N = 512, Hm = 1024;
  const size_t SZ = (size_t)T * B * C * N;  // u8 spike buffers

  // Workspace (u8), peak 5*SZ = 41.9 MB; h overlays dead q/k/v/r.
  char* ws = (char*)d_ws;
  u8* q_s  = (u8*)(ws + 0 * SZ);
  u8* k_s  = (u8*)(ws + 1 * SZ);
  u8* v_s  = (u8*)(ws + 2 * SZ);
  u8* r_s  = (u8*)(ws + 3 * SZ);
  u8* ao_s = (u8*)(ws + 4 * SZ);
  u8* h_s  = (u8*)(ws + 0 * SZ);

  dim3 blk(256);
  dim3 gC(N / 64, C / 64, B);

  conv_bn_lif<0, false, 0><<<gC, blk, 0, stream>>>(
      x, nullptr, q_w, nullptr, q_bn, q_s, nullptr, nullptr, nullptr, B, C, C, N);
  conv_bn_lif<0, false, 0><<<gC, blk, 0, stream>>>(
      x, nullptr, k_w, nullptr, k_bn, k_s, nullptr, nullptr, nullptr, B, C, C, N);
  conv_bn_lif<0, false, 0><<<gC, blk, 0, stream>>>(
      x, nullptr, v_w, nullptr, v_bn, v_s, nullptr, nullptr, nullptr, B, C, C, N);
  attn_lif<<<dim3(B * 16), blk, 0, stream>>>(q_s, k_s, v_s, r_s, B, C, N);
  conv_bn_lif<1, false, 0><<<gC, blk, 0, stream>>>(
      r_s, nullptr, p_w, nullptr, p_bn, ao_s, nullptr, nullptr, nullptr, B, C, C, N);
  conv_bn_lif<0, true, 0><<<dim3(N / 64, Hm / 64, B), blk, 0, stream>>>(
      x, ao_s, f1_w, f1_b, f1_bn, h_s, nullptr, nullptr, nullptr, B, C, Hm, N);
  conv_bn_lif<1, false, 1><<<gC, blk, 0, stream>>>(
      h_s, nullptr, f2_w, f2_b, f2_bn, nullptr, x, ao_s, (float*)d_out, B, Hm, C, N);
}